// Round 1
// baseline (418.891 us; speedup 1.0000x reference)
//
#include <hip/hip_runtime.h>

// ARNOLD_ENC: spike-latency encoding.
//   bin(b,n) = int(2.5*|trace[b,f]-center[c]| / 0.1 + 1); spike at t=bin iff times<=10 and bin<100.
//   out: int32[100][1024][1024] = 400 MiB. Store-BW bound; ~66.3 us floor at the fill's 6.33 TB/s.
//
// Measurement decomposition (R4): per timed iter = d_ws poison 1600 MiB (265 us, fixed) +
//   d_out poison 400 MiB (~66 us, fixed) + our kernels (~87 us). Controllable headroom ~20 us.
// R1: t-strided 4KB bursts, regular stores  -> ~95 us kernels
// R2: contiguous stream, regular stores     -> ~92 us (pattern: neutral)
// R4: contiguous stream, nontemporal stores -> ~89 us (NT: -3 us)
// R5 (this): FUSE bins compute into the store kernel, bins held in REGISTERS.
//   Window=2048 groups spans exactly 8 b-rows with b_local == i, so thread tid needs only
//   trace[(w*8+i)*128 + (tid>>1)] for i=0..7 -> its 32 bins are thread-private. Drop the
//   bins kernel, the 1 MiB ws roundtrip, LDS staging and __syncthreads entirely: single
//   dispatch, pure NT-store stream like fillBufferAligned (which hits 6.3 TB/s at 10% occ).

#define BB 1024
#define FF 128
#define NN 1024
#define TT 100
#define PLANE_GROUPS ((BB * NN) / 4)        // 262144 int4 groups per t-plane
#define WINDOW 2048                          // groups per window = 8 b-rows x 256 groups
#define WINS (PLANE_GROUPS / WINDOW)         // 128 windows per plane
#define PCH 10                               // planes per block
#define PCHUNKS (TT / PCH)                   // 10

typedef int iv4 __attribute__((ext_vector_type(4)));   // native vector for nontemporal builtin

__global__ __launch_bounds__(256) void arnold_fused_kernel(
        const float* __restrict__ trace,
        const float* __restrict__ center,
        iv4* __restrict__ out) {
    const int w   = blockIdx.x;      // 0..127  window within plane (8 b-rows)
    const int pc  = blockIdx.y;      // 0..9    plane chunk
    const int tid = threadIdx.x;     // 0..255

    // Thread's lane within a plane-row: group g = i*256 + tid -> b_local = i, n0 = 4*tid.
    const int f  = tid >> 1;                 // feature index (two threads per feature)
    const int c0 = (tid & 1) << 2;           // first of 4 consecutive centers

    float c[4];
#pragma unroll
    for (int j = 0; j < 4; ++j) c[j] = center[c0 + j];

    // Compute this thread's 32 bins (8 b-rows x 4 centers) in registers.
    // IEEE f32 (no fast-math): matches np/jnp binning bit-exactly (verified in prior rounds).
    unsigned bb[8][4];
#pragma unroll
    for (int i = 0; i < 8; ++i) {
        const float x = trace[(w * 8 + i) * FF + f];
#pragma unroll
        for (int j = 0; j < 4; ++j) {
            float tms = 2.5f * fabsf(x - c[j]);
            bb[i][j] = (tms > 10.0f) ? 255u : (unsigned)(tms / 0.1f + 1.0f);  // 1..101 or 255
        }
    }

    // Pure store stream: 10 planes x 8 groups, 32 KB contiguous burst per plane.
    const int t0 = pc * PCH;
    iv4* op = out + (size_t)t0 * PLANE_GROUPS + w * WINDOW + tid;
    for (int tt = 0; tt < PCH; ++tt) {
        const unsigned t = (unsigned)(t0 + tt);
#pragma unroll
        for (int i = 0; i < 8; ++i) {
            iv4 v;
            v.x = (bb[i][0] == t) ? 1 : 0;
            v.y = (bb[i][1] == t) ? 1 : 0;
            v.z = (bb[i][2] == t) ? 1 : 0;
            v.w = (bb[i][3] == t) ? 1 : 0;
            __builtin_nontemporal_store(v, op + i * 256);   // coalesced 1 KB/wave-instr
        }
        op += PLANE_GROUPS;
    }
}

extern "C" void kernel_launch(void* const* d_in, const int* in_sizes, int n_in,
                              void* d_out, int out_size, void* d_ws, size_t ws_size,
                              hipStream_t stream) {
    const float* trace  = (const float*)d_in[0];   // [1024,128] f32
    const float* center = (const float*)d_in[1];   // [8] f32
    iv4* out = (iv4*)d_out;                        // [100][1024][1024] int32
    (void)d_ws; (void)ws_size;                     // workspace no longer used

    dim3 grid(WINS, PCHUNKS);                      // (128, 10) = 1280 blocks, 5/CU, all resident
    arnold_fused_kernel<<<grid, 256, 0, stream>>>(trace, center, out);
}

// Round 2
// 411.506 us; speedup vs baseline: 1.0179x; 1.0179x over previous
//
#include <hip/hip_runtime.h>

// ARNOLD_ENC: spike-latency encoding.
//   bin(b,n) = int(2.5*|trace[b,f]-center[c]| / 0.1 + 1); spike at t=bin iff bin<100.
//   out: int32[100][1024][1024] = 400 MiB. Store-BW bound; ~66.3 us floor at fill's 6.33 TB/s.
//
// Measurement decomposition: per timed iter = d_ws poison 1600 MiB (~267 us, fixed) +
//   d_out poison 400 MiB (~67 us, fixed) + our kernels. Controllable region ~85 us as of R5.
// R1: t-strided 4KB bursts, regular stores   -> ~95 us kernels
// R2: contiguous stream, regular stores      -> ~92 us (pattern within block: neutral)
// R4: contiguous stream, nontemporal stores  -> ~89 us (NT: -3 us)
// R5: fused single kernel, bins in registers -> ~85 us (still 4.9 TB/s vs fill's 6.3)
// R6 (this): fill is faster NOT because of its instruction stream (8 VGPR, 10% occ) but
//   because grid-stride with a small grid makes the instantaneous write window a compact
//   ~1 MB region SWEEPING linearly -> perfect HBM page locality. R5's 2048 waves park on
//   128 windows x 10 plane-chunks = whole 400 MiB hot at once, 1KB@4KB-stride bursts.
//   Fix: bins pre-pass (1 MiB ws, divisions paid once) + 512-block grid-stride sweep in
//   pure output-linear order (2 MiB sliding window, 200 iters/thread exact). NT stores so
//   the write stream doesn't evict the L2-resident bins window.

#define BB 1024
#define FF 128
#define TT 100
#define PLANE_GROUPS ((BB * 1024) / 4)          // 262144 iv4 groups per t-plane (4 MiB)
#define TOTAL_GROUPS (TT * PLANE_GROUPS)        // 26,214,400 groups = 400 MiB
#define SWEEP_BLOCKS 512
#define SWEEP_STRIDE (SWEEP_BLOCKS * 256)       // 131072 threads = 2 MiB sliding window
#define SWEEP_ITERS (TOTAL_GROUPS / SWEEP_STRIDE) // exactly 200, no remainder

typedef int iv4 __attribute__((ext_vector_type(4)));   // native vector for nontemporal builtin

// Pre-pass: one byte per (b, n-group-lane): bin index 1..101 or 255 (never matches t<100).
// IEEE f32 (no fast-math): matches np/jnp binning bit-exactly (verified passing R1-R5).
__global__ __launch_bounds__(256) void arnold_bins_kernel(
        const float* __restrict__ trace,
        const float* __restrict__ center,
        uchar4* __restrict__ bins) {
    const int b   = blockIdx.x;      // 0..1023
    const int tid = threadIdx.x;     // 0..255
    const int n0  = tid << 2;        // 4 consecutive n, same f
    const int f   = n0 >> 3;
    const int c0  = n0 & 7;

    const float x = trace[b * FF + f];

    unsigned char v[4];
#pragma unroll
    for (int i = 0; i < 4; ++i) {
        float tms = 2.5f * fabsf(x - center[c0 + i]);
        unsigned bb = (tms > 10.0f) ? 255u : (unsigned)(tms / 0.1f + 1.0f);  // 1..101 or 255
        v[i] = (unsigned char)bb;
    }
    bins[(b << 8) + tid] = make_uchar4(v[0], v[1], v[2], v[3]);
}

// Sweep: grid-stride in output-linear order, fill-isomorphic write pattern.
__global__ __launch_bounds__(256) void arnold_sweep_kernel(
        const uchar4* __restrict__ bins,
        iv4* __restrict__ out) {
    unsigned g = blockIdx.x * 256u + threadIdx.x;   // group index, < 2^25
#pragma unroll 4
    for (int k = 0; k < SWEEP_ITERS; ++k) {
        const unsigned t = g >> 18;                 // plane index 0..99 (wave-uniform)
        const uchar4 c = bins[g & (PLANE_GROUPS - 1)];  // 4B L2-resident load
        iv4 v;
        v.x = (c.x == t) ? 1 : 0;
        v.y = (c.y == t) ? 1 : 0;
        v.z = (c.z == t) ? 1 : 0;
        v.w = (c.w == t) ? 1 : 0;
        __builtin_nontemporal_store(v, out + g);    // coalesced 1 KB/wave-instr
        g += SWEEP_STRIDE;
    }
}

extern "C" void kernel_launch(void* const* d_in, const int* in_sizes, int n_in,
                              void* d_out, int out_size, void* d_ws, size_t ws_size,
                              hipStream_t stream) {
    const float* trace  = (const float*)d_in[0];   // [1024,128] f32
    const float* center = (const float*)d_in[1];   // [8] f32
    uchar4* bins = (uchar4*)d_ws;                  // 1 MiB scratch, fully rewritten each call
    iv4* out = (iv4*)d_out;                        // [100][1024][1024] int32

    arnold_bins_kernel<<<BB, 256, 0, stream>>>(trace, center, bins);
    arnold_sweep_kernel<<<SWEEP_BLOCKS, 256, 0, stream>>>(bins, out);
}

// Round 3
// 407.883 us; speedup vs baseline: 1.0270x; 1.0089x over previous
//
#include <hip/hip_runtime.h>

// ARNOLD_ENC: spike-latency encoding.
//   bin(b,n) = int(2.5*|trace[b,f]-center[c]| / 0.1 + 1); spike at t=bin iff bin<=99.
//   out: int32[100][1024][1024] = 400 MiB. Store-BW bound; ~66.3 us floor at fill's 6.33 TB/s.
//
// Measurement decomposition: per timed iter = d_ws poison 1600 MiB (~266 us, fixed) +
//   d_out poison 400 MiB (~66 us, fixed) + our kernels. Controllable region ~79 us as of R6.
// R1: t-strided 4KB bursts, regular stores    -> ~95 us kernels
// R2: contiguous stream, regular stores       -> ~92 us (pattern within block: neutral)
// R4: contiguous stream, nontemporal stores   -> ~89 us (NT: -3 us)
// R5: fused parked-window kernel, bins in reg -> ~85 us (whole 400 MiB hot at once: bad)
// R6: bins pre-pass + 512-block linear sweep  -> ~79 us (sweep 5.5 TB/s; fill-like window helped)
// R7 (this): kill the last load in the loop. With stride = PLANE_GROUPS/2, a thread's bins
//   index alternates between exactly TWO values (g0, g0+2^17) and t = k>>1 uniformly. So each
//   thread needs only 8 bin bytes total -> compute them in registers from 2 trace floats at
//   start (bins pre-pass and d_ws gone). Loop = 8 compares + 2 NT stores, no loads, no
//   waitcnt -> instruction-stream-isomorphic to fillBufferAligned (6.3 TB/s at 10% occ).

#define FF 128
#define TT 100
#define PLANE_GROUPS ((1024 * 1024) / 4)     // 262144 iv4 groups per t-plane (4 MiB)
#define HALF_PLANE (PLANE_GROUPS / 2)        // 131072 = sweep stride
#define SWEEP_BLOCKS 512                     // 512*256 threads cover exactly half a plane

typedef int iv4 __attribute__((ext_vector_type(4)));   // native vector for nontemporal builtin

__global__ __launch_bounds__(256) void arnold_sweep_fused(
        const float* __restrict__ trace,
        const float* __restrict__ center,
        iv4* __restrict__ out) {
    const int b0  = blockIdx.x;      // 0..511  (even-k row; odd-k row is b0+512)
    const int tid = threadIdx.x;     // 0..255  (= group-in-row; constant across iters)
    const int f   = tid >> 1;        // feature index (two threads per feature)
    const int c0  = (tid & 1) << 2;  // first of 4 consecutive centers

    float cc[4];
#pragma unroll
    for (int j = 0; j < 4; ++j) cc[j] = center[c0 + j];

    const float x0 = trace[b0 * FF + f];           // row b0      (even k)
    const float x1 = trace[(b0 + 512) * FF + f];   // row b0+512  (odd k)

    // This thread's 8 bins, in registers. IEEE f32 (no fast-math): matches jnp bit-exactly
    // (same expression verified passing in R1-R6). Values 1..101 or 255; t<=99 never
    // matches 100/101/255, reproducing the reference mask.
    unsigned bin0[4], bin1[4];
#pragma unroll
    for (int j = 0; j < 4; ++j) {
        float t0 = 2.5f * fabsf(x0 - cc[j]);
        bin0[j] = (t0 > 10.0f) ? 255u : (unsigned)(t0 / 0.1f + 1.0f);
        float t1 = 2.5f * fabsf(x1 - cc[j]);
        bin1[j] = (t1 > 10.0f) ? 255u : (unsigned)(t1 / 0.1f + 1.0f);
    }

    // Pure store stream: per t-plane, two 16B NT stores (rows b0 and b0+512), then jump
    // one plane. No loads, no waitcnt in the loop. Grid sweeps output linearly like fill.
    iv4* p = out + (unsigned)(b0 * 256 + tid);
#pragma unroll 4
    for (unsigned t = 0; t < TT; ++t) {
        iv4 v0, v1;
        v0.x = (bin0[0] == t) ? 1 : 0;
        v0.y = (bin0[1] == t) ? 1 : 0;
        v0.z = (bin0[2] == t) ? 1 : 0;
        v0.w = (bin0[3] == t) ? 1 : 0;
        v1.x = (bin1[0] == t) ? 1 : 0;
        v1.y = (bin1[1] == t) ? 1 : 0;
        v1.z = (bin1[2] == t) ? 1 : 0;
        v1.w = (bin1[3] == t) ? 1 : 0;
        __builtin_nontemporal_store(v0, p);               // coalesced 1 KB/wave-instr
        __builtin_nontemporal_store(v1, p + HALF_PLANE);
        p += PLANE_GROUPS;
    }
}

extern "C" void kernel_launch(void* const* d_in, const int* in_sizes, int n_in,
                              void* d_out, int out_size, void* d_ws, size_t ws_size,
                              hipStream_t stream) {
    const float* trace  = (const float*)d_in[0];   // [1024,128] f32
    const float* center = (const float*)d_in[1];   // [8] f32
    iv4* out = (iv4*)d_out;                        // [100][1024][1024] int32
    (void)d_ws; (void)ws_size;                     // workspace no longer needed

    arnold_sweep_fused<<<SWEEP_BLOCKS, 256, 0, stream>>>(trace, center, out);
}